// Round 2
// baseline (4109.569 us; speedup 1.0000x reference)
//
#include <hip/hip_runtime.h>

typedef float fv4 __attribute__((ext_vector_type(4)));
typedef __bf16 bfv8 __attribute__((ext_vector_type(8)));
typedef unsigned short u16v4 __attribute__((ext_vector_type(4)));
typedef unsigned short u16v8 __attribute__((ext_vector_type(8)));

#define B_DIM 4
#define L_DIM 8192
#define D_DIM 1024
#define H_NUM 16
#define NSEG 16
#define SEG_S 512
#define MB_TOK L_DIM  // rows per batch element: 8192

__device__ __forceinline__ unsigned short f2bf(float f) {
  unsigned u = __float_as_uint(f);
  u += 0x7fffu + ((u >> 16) & 1u);  // RNE
  return (unsigned short)(u >> 16);
}
__device__ __forceinline__ float bf2f(unsigned short h) {
  return __uint_as_float((unsigned)h << 16);
}

// ---------------- fp32 -> (bf16 hi, bf16 lo) split ----------------
__global__ __launch_bounds__(256) void split_f32_bf16x2(
    const float* __restrict__ in, unsigned short* __restrict__ hi,
    unsigned short* __restrict__ lo, int n4) {
  int i = blockIdx.x * 256 + threadIdx.x;
  const int stride = gridDim.x * 256;
  for (; i < n4; i += stride) {
    fv4 v = reinterpret_cast<const fv4*>(in)[i];
    u16v4 hv, lv;
#pragma unroll
    for (int j = 0; j < 4; ++j) {
      unsigned short h = f2bf(v[j]);
      hv[j] = h;
      lv[j] = f2bf(v[j] - bf2f(h));
    }
    reinterpret_cast<u16v4*>(hi)[i] = hv;
    reinterpret_cast<u16v4*>(lo)[i] = lv;
  }
}

// ---------------- C[M,N] = A @ B^T, split-bf16 3-product MFMA ----------------
// A: M x K (hi/lo), B: N x K (hi/lo), row-major, K contiguous. C fp32 (+bias[N]).
// 128x128 tile, 256 threads = 4 waves (2x2), each wave 64x64 = 4x4 frags of 16x16x32.
#define GT_PAD 40  // 32 + 8 pad elements -> 80B row stride (16B aligned, ~2-way banks)
__global__ __launch_bounds__(256) void gemm_bt_split(
    const __bf16* __restrict__ Ah, const __bf16* __restrict__ Al,
    const __bf16* __restrict__ Bh, const __bf16* __restrict__ Bl,
    float* __restrict__ C, const float* __restrict__ bias,
    int M, int N, int K) {
  __shared__ __bf16 sAh[128 * GT_PAD], sAl[128 * GT_PAD];
  __shared__ __bf16 sBh[128 * GT_PAD], sBl[128 * GT_PAD];
  const int tid = threadIdx.x;
  const int lane = tid & 63;
  const int wid = tid >> 6;
  const int wr = wid >> 1, wc = wid & 1;
  const int mBase = blockIdx.y * 128;
  const int nBase = blockIdx.x * 128;

  fv4 acc[4][4] = {};

  const int arowRd = wr * 64 + (lane & 15);
  const int browRd = wc * 64 + (lane & 15);
  const int koff = (lane >> 4) << 3;  // k = 8*(lane/16)

  for (int k0 = 0; k0 < K; k0 += 32) {
    __syncthreads();  // previous iter's frag reads done before overwrite
#pragma unroll
    for (int it = 0; it < 2; ++it) {
      const int idx = it * 256 + tid;       // 0..511
      const int row = idx >> 2, ch = idx & 3;
      const int ldo = row * GT_PAD + ch * 8;
      const long ga = (long)(mBase + row) * K + k0 + ch * 8;
      const long gb = (long)(nBase + row) * K + k0 + ch * 8;
      *(bfv8*)&sAh[ldo] = *(const bfv8*)&Ah[ga];
      *(bfv8*)&sAl[ldo] = *(const bfv8*)&Al[ga];
      *(bfv8*)&sBh[ldo] = *(const bfv8*)&Bh[gb];
      *(bfv8*)&sBl[ldo] = *(const bfv8*)&Bl[gb];
    }
    __syncthreads();
    bfv8 fah[4], fal[4], fbh[4], fbl[4];
#pragma unroll
    for (int i = 0; i < 4; ++i) {
      fah[i] = *(const bfv8*)&sAh[(arowRd + i * 16) * GT_PAD + koff];
      fal[i] = *(const bfv8*)&sAl[(arowRd + i * 16) * GT_PAD + koff];
      fbh[i] = *(const bfv8*)&sBh[(browRd + i * 16) * GT_PAD + koff];
      fbl[i] = *(const bfv8*)&sBl[(browRd + i * 16) * GT_PAD + koff];
    }
#pragma unroll
    for (int i = 0; i < 4; ++i)
#pragma unroll
      for (int j = 0; j < 4; ++j) {
        acc[i][j] = __builtin_amdgcn_mfma_f32_16x16x32_bf16(fah[i], fbh[j], acc[i][j], 0, 0, 0);
        acc[i][j] = __builtin_amdgcn_mfma_f32_16x16x32_bf16(fah[i], fbl[j], acc[i][j], 0, 0, 0);
        acc[i][j] = __builtin_amdgcn_mfma_f32_16x16x32_bf16(fal[i], fbh[j], acc[i][j], 0, 0, 0);
      }
  }

  // C/D layout (verified m89): col = lane&15, row = 4*(lane>>4) + reg
  const int crow0 = mBase + wr * 64 + ((lane >> 4) << 2);
  const int ccol0 = nBase + wc * 64 + (lane & 15);
#pragma unroll
  for (int j = 0; j < 4; ++j) {
    const int col = ccol0 + j * 16;
    const float bv = bias ? bias[col] : 0.f;
#pragma unroll
    for (int i = 0; i < 4; ++i) {
      const long rb = (long)(crow0 + i * 16) * N + col;
#pragma unroll
      for (int r = 0; r < 4; ++r)
        C[rb + (long)r * N] = acc[i][j][r] + bv;
    }
  }
}

// ---------------- per-(seg,h) outer products for ONE batch element ----------------
// U[d][e] = sum_s ak[s,d]*v[s,e],  Zs[d] = sum_s ak[s,d]
__global__ __launch_bounds__(256) void seg_outer(
    const float* __restrict__ Kf, const float* __restrict__ Vf,
    float* __restrict__ U, float* __restrict__ Zs) {
  const int sh = blockIdx.x;  // seg*16 + h
  const int seg = sh >> 4, h = sh & 15;
  const int tid = threadIdx.x;
  const int dgrp = tid >> 6, e = tid & 63;
  __shared__ float sAK[16 * 64], sVv[16 * 64];
  const long base = ((long)seg * SEG_S) * D_DIM + h * 64;
  float acc[16] = {};
  float zacc = 0.f;
  for (int s0 = 0; s0 < SEG_S; s0 += 16) {
    __syncthreads();
#pragma unroll
    for (int r = 0; r < 4; ++r) {
      const int idx = r * 256 + tid;  // 0..1023
      const int sl = idx >> 6, d = idx & 63;
      const long g = base + (long)(s0 + sl) * D_DIM + d;
      const float kv = Kf[g];
      sAK[idx] = kv > 0.f ? kv + 1.f : __expf(kv);  // elu(k)+1
      sVv[idx] = Vf[g];
    }
    __syncthreads();
#pragma unroll
    for (int sl = 0; sl < 16; ++sl) {
      const float vv = sVv[sl * 64 + e];
#pragma unroll
      for (int i = 0; i < 16; ++i)
        acc[i] += sAK[sl * 64 + dgrp * 16 + i] * vv;
    }
    if (tid < 64) {
#pragma unroll
      for (int sl = 0; sl < 16; ++sl) zacc += sAK[sl * 64 + tid];
    }
  }
  const long ub = (long)sh * 4096;
#pragma unroll
  for (int i = 0; i < 16; ++i)
    U[ub + (dgrp * 16 + i) * 64 + e] = acc[i];
  if (tid < 64) Zs[(long)sh * 64 + tid] = zacc;
}

// ---------------- exclusive prefix over segments for ONE batch element ----------------
__global__ __launch_bounds__(256) void seg_prefix(
    const float* __restrict__ U, const float* __restrict__ Zs,
    float* __restrict__ Mem, float* __restrict__ Zp) {
  const int h = blockIdx.x;  // 0..15
  const int tid = threadIdx.x;
  for (int j = tid; j < 4096; j += 256) {
    float run = 0.f;
#pragma unroll
    for (int t = 0; t < NSEG; ++t) {
      const long idx = ((long)(t * 16 + h)) * 4096 + j;
      Mem[idx] = run;
      run += U[idx];
    }
  }
  if (tid < 64) {
    float run = 0.f;
#pragma unroll
    for (int t = 0; t < NSEG; ++t) {
      const long idx = ((long)(t * 16 + h)) * 64 + tid;
      Zp[idx] = run;
      run += Zs[idx];
    }
  }
}

// ---------------- segment SDPA + memory read + gate for ONE batch element ----------------
__global__ __launch_bounds__(256) void attn_seg(
    const float* __restrict__ Qf, const float* __restrict__ Kf,
    const float* __restrict__ Vf, const int* __restrict__ mask,
    const float* __restrict__ Mem, const float* __restrict__ Zp,
    const float* __restrict__ betas,
    unsigned short* __restrict__ Oh, unsigned short* __restrict__ Ol) {
  const int blk = blockIdx.x;         // 2 blocks per (seg,h)
  const int sh = blk >> 1;
  const int half = blk & 1;
  const int seg = sh >> 4, h = sh & 15;
  const int tid = threadIdx.x;
  const int s = half * 256 + tid;     // query row within segment

  __shared__ float sK[64 * 64], sV[64 * 64], sMem[4096];
  __shared__ float sZ[64], sGate[64];
  __shared__ int sMask[64];

  const long rowbase = (long)seg * SEG_S;
  const long qoff = (rowbase + s) * D_DIM + h * 64;
  float q[64];
#pragma unroll
  for (int d4 = 0; d4 < 16; ++d4) {
    fv4 v = *(const fv4*)&Qf[qoff + d4 * 4];
#pragma unroll
    for (int j = 0; j < 4; ++j) q[d4 * 4 + j] = v[j];
  }

  float mrun = -3.0e38f, lsum = 0.f;
  float acc[64] = {};

  for (int c = 0; c < 8; ++c) {  // 8 chunks of 64 keys
    __syncthreads();
#pragma unroll
    for (int r = 0; r < 16; ++r) {
      const int idx = r * 256 + tid;  // 0..4095
      const int srow = idx >> 6, d = idx & 63;
      const long g = (rowbase + c * 64 + srow) * D_DIM + h * 64 + d;
      sK[idx] = Kf[g];
      sV[idx] = Vf[g];
    }
    if (tid < 64) sMask[tid] = mask[seg * SEG_S + c * 64 + tid];
    __syncthreads();
    for (int t = 0; t < 64; ++t) {
      float s0 = 0.f, s1 = 0.f, s2 = 0.f, s3 = 0.f;
#pragma unroll
      for (int d = 0; d < 16; ++d) {
        s0 += q[d] * sK[t * 64 + d];
        s1 += q[16 + d] * sK[t * 64 + 16 + d];
        s2 += q[32 + d] * sK[t * 64 + 32 + d];
        s3 += q[48 + d] * sK[t * 64 + 48 + d];
      }
      float sc = (s0 + s1) + (s2 + s3);
      sc *= 0.125f;  // 1/sqrt(64)
      if (sMask[t] == 0) sc = -1e9f;
      if (sc > mrun) {
        const float resc = __expf(mrun - sc);
        lsum *= resc;
#pragma unroll
        for (int e = 0; e < 64; ++e) acc[e] *= resc;
        mrun = sc;
      }
      const float p = __expf(sc - mrun);
      lsum += p;
#pragma unroll
      for (int e = 0; e < 64; ++e) acc[e] += p * sV[t * 64 + e];
    }
  }

  __syncthreads();
  for (int j = tid; j < 4096; j += 256) sMem[j] = Mem[(long)sh * 4096 + j];
  if (tid < 64) {
    sZ[tid] = Zp[(long)sh * 64 + tid];
    sGate[tid] = 1.f / (1.f + __expf(-betas[h * 64 + tid]));
  }
  __syncthreads();

  // aq = elu(q)+1 (reuse q regs)
#pragma unroll
  for (int d = 0; d < 64; ++d) q[d] = q[d] > 0.f ? q[d] + 1.f : __expf(q[d]);
  float denom = 1e-9f;
#pragma unroll
  for (int d = 0; d < 64; ++d) denom += q[d] * sZ[d];
  const float invl = 1.f / lsum;
  const float invden = 1.f / denom;

  const long obase = (rowbase + s) * D_DIM + h * 64;
#pragma unroll
  for (int eg = 0; eg < 8; ++eg) {
    float tmp[8] = {};
#pragma unroll
    for (int d = 0; d < 64; ++d) {
      const float aqd = q[d];
#pragma unroll
      for (int j = 0; j < 8; ++j) tmp[j] += aqd * sMem[d * 64 + eg * 8 + j];
    }
    u16v8 hv, lv;
#pragma unroll
    for (int j = 0; j < 8; ++j) {
      const int e = eg * 8 + j;
      const float att = sGate[e] * (tmp[j] * invden) + (1.f - sGate[e]) * (acc[e] * invl);
      const unsigned short hb = f2bf(att);
      hv[j] = hb;
      lv[j] = f2bf(att - bf2f(hb));
    }
    *(u16v8*)&Oh[obase + eg * 8] = hv;
    *(u16v8*)&Ol[obase + eg * 8] = lv;
  }
}

// ---------------- host launch: batch-tiled to bound workspace ----------------
extern "C" void kernel_launch(void* const* d_in, const int* in_sizes, int n_in,
                              void* d_out, int out_size, void* d_ws, size_t ws_size,
                              hipStream_t stream) {
  (void)in_sizes; (void)n_in; (void)out_size;
  const float* x     = (const float*)d_in[0];
  const int*   mask  = (const int*)d_in[1];
  const float* wq    = (const float*)d_in[2];
  const float* wk    = (const float*)d_in[3];
  const float* wv    = (const float*)d_in[4];
  const float* wo    = (const float*)d_in[5];
  const float* wob   = (const float*)d_in[6];
  const float* betas = (const float*)d_in[7];
  float* out = (float*)d_out;

  const size_t TOKB = (size_t)MB_TOK * D_DIM;  // 8,388,608 elements per batch
  char* ws = (char*)d_ws;
  size_t off = 0;
  auto alloc = [&](size_t bytes) {
    char* p = ws + off;
    off += (bytes + 255) & ~(size_t)255;
    return p;
  };
  // weight splits (persistent): 8 x 2 MiB
  unsigned short* wsp[8];
  for (int i = 0; i < 8; ++i)
    wsp[i] = (unsigned short*)alloc((size_t)D_DIM * D_DIM * 2);
  // per-batch-element buffers (reused across b)
  unsigned short* xh = (unsigned short*)alloc(TOKB * 2);  // 16 MiB
  unsigned short* xl = (unsigned short*)alloc(TOKB * 2);
  float* qf = (float*)alloc(TOKB * 4);                    // 32 MiB
  float* kf = (float*)alloc(TOKB * 4);
  float* vf = (float*)alloc(TOKB * 4);
  float* U   = (float*)alloc((size_t)NSEG * H_NUM * 4096 * 4);  // 4 MiB
  float* Mem = (float*)alloc((size_t)NSEG * H_NUM * 4096 * 4);
  float* Zs  = (float*)alloc((size_t)NSEG * H_NUM * 64 * 4);
  float* Zp  = (float*)alloc((size_t)NSEG * H_NUM * 64 * 4);
  // att split output reuses xh/xl (x_b is dead after the QKV GEMMs)
  unsigned short* atth = xh;
  unsigned short* attl = xl;

  if (off > ws_size) return;  // workspace too small: fail cleanly, don't fault

  // weight splits once
  const float* wsrc[4] = {wq, wk, wv, wo};
  for (int i = 0; i < 4; ++i)
    split_f32_bf16x2<<<1024, 256, 0, stream>>>(wsrc[i], wsp[2 * i], wsp[2 * i + 1],
                                               D_DIM * D_DIM / 4);

  dim3 ggrid(D_DIM / 128, MB_TOK / 128);
  for (int b = 0; b < B_DIM; ++b) {
    const float* xb = x + (size_t)b * TOKB;
    const int* maskb = mask + (size_t)b * L_DIM;
    float* outb = out + (size_t)b * TOKB;

    split_f32_bf16x2<<<2048, 256, 0, stream>>>(xb, xh, xl, (int)(TOKB / 4));

    gemm_bt_split<<<ggrid, 256, 0, stream>>>(
        (const __bf16*)xh, (const __bf16*)xl, (const __bf16*)wsp[0], (const __bf16*)wsp[1],
        qf, nullptr, MB_TOK, D_DIM, D_DIM);
    gemm_bt_split<<<ggrid, 256, 0, stream>>>(
        (const __bf16*)xh, (const __bf16*)xl, (const __bf16*)wsp[2], (const __bf16*)wsp[3],
        kf, nullptr, MB_TOK, D_DIM, D_DIM);
    gemm_bt_split<<<ggrid, 256, 0, stream>>>(
        (const __bf16*)xh, (const __bf16*)xl, (const __bf16*)wsp[4], (const __bf16*)wsp[5],
        vf, nullptr, MB_TOK, D_DIM, D_DIM);

    seg_outer<<<NSEG * H_NUM, 256, 0, stream>>>(kf, vf, U, Zs);
    seg_prefix<<<H_NUM, 256, 0, stream>>>(U, Zs, Mem, Zp);

    attn_seg<<<NSEG * H_NUM * 2, 256, 0, stream>>>(qf, kf, vf, maskb, Mem, Zp, betas,
                                                   atth, attl);

    gemm_bt_split<<<ggrid, 256, 0, stream>>>(
        (const __bf16*)atth, (const __bf16*)attl, (const __bf16*)wsp[6], (const __bf16*)wsp[7],
        outb, wob, MB_TOK, D_DIM, D_DIM);
  }
}

// Round 3
// 1837.180 us; speedup vs baseline: 2.2369x; 2.2369x over previous
//
#include <hip/hip_runtime.h>

typedef float fv4 __attribute__((ext_vector_type(4)));
typedef __bf16 bfv8 __attribute__((ext_vector_type(8)));
typedef unsigned short u16v2 __attribute__((ext_vector_type(2)));
typedef unsigned short u16v4 __attribute__((ext_vector_type(4)));
typedef unsigned short u16v8 __attribute__((ext_vector_type(8)));

#define B_DIM 4
#define L_DIM 8192
#define D_DIM 1024
#define H_NUM 16
#define NSEG 16
#define SEG_S 512
#define MB_TOK L_DIM  // rows per batch element: 8192

__device__ __forceinline__ unsigned short f2bf(float f) {
  unsigned u = __float_as_uint(f);
  u += 0x7fffu + ((u >> 16) & 1u);  // RNE
  return (unsigned short)(u >> 16);
}
__device__ __forceinline__ float bf2f(unsigned short h) {
  return __uint_as_float((unsigned)h << 16);
}

// ---------------- fp32 -> (bf16 hi, bf16 lo) split ----------------
__global__ __launch_bounds__(256) void split_f32_bf16x2(
    const float* __restrict__ in, unsigned short* __restrict__ hi,
    unsigned short* __restrict__ lo, int n4) {
  int i = blockIdx.x * 256 + threadIdx.x;
  const int stride = gridDim.x * 256;
  for (; i < n4; i += stride) {
    fv4 v = reinterpret_cast<const fv4*>(in)[i];
    u16v4 hv, lv;
#pragma unroll
    for (int j = 0; j < 4; ++j) {
      unsigned short h = f2bf(v[j]);
      hv[j] = h;
      lv[j] = f2bf(v[j] - bf2f(h));
    }
    reinterpret_cast<u16v4*>(hi)[i] = hv;
    reinterpret_cast<u16v4*>(lo)[i] = lv;
  }
}

// ---------------- C[M,N] = A @ B^T, split-bf16 3-product MFMA ----------------
#define GT_PAD 40
__global__ __launch_bounds__(256) void gemm_bt_split(
    const __bf16* __restrict__ Ah, const __bf16* __restrict__ Al,
    const __bf16* __restrict__ Bh, const __bf16* __restrict__ Bl,
    float* __restrict__ C, const float* __restrict__ bias,
    int M, int N, int K) {
  __shared__ __bf16 sAh[128 * GT_PAD], sAl[128 * GT_PAD];
  __shared__ __bf16 sBh[128 * GT_PAD], sBl[128 * GT_PAD];
  const int tid = threadIdx.x;
  const int lane = tid & 63;
  const int wid = tid >> 6;
  const int wr = wid >> 1, wc = wid & 1;
  const int mBase = blockIdx.y * 128;
  const int nBase = blockIdx.x * 128;

  fv4 acc[4][4] = {};

  const int arowRd = wr * 64 + (lane & 15);
  const int browRd = wc * 64 + (lane & 15);
  const int koff = (lane >> 4) << 3;

  for (int k0 = 0; k0 < K; k0 += 32) {
    __syncthreads();
#pragma unroll
    for (int it = 0; it < 2; ++it) {
      const int idx = it * 256 + tid;
      const int row = idx >> 2, ch = idx & 3;
      const int ldo = row * GT_PAD + ch * 8;
      const long ga = (long)(mBase + row) * K + k0 + ch * 8;
      const long gb = (long)(nBase + row) * K + k0 + ch * 8;
      *(bfv8*)&sAh[ldo] = *(const bfv8*)&Ah[ga];
      *(bfv8*)&sAl[ldo] = *(const bfv8*)&Al[ga];
      *(bfv8*)&sBh[ldo] = *(const bfv8*)&Bh[gb];
      *(bfv8*)&sBl[ldo] = *(const bfv8*)&Bl[gb];
    }
    __syncthreads();
    bfv8 fah[4], fal[4], fbh[4], fbl[4];
#pragma unroll
    for (int i = 0; i < 4; ++i) {
      fah[i] = *(const bfv8*)&sAh[(arowRd + i * 16) * GT_PAD + koff];
      fal[i] = *(const bfv8*)&sAl[(arowRd + i * 16) * GT_PAD + koff];
      fbh[i] = *(const bfv8*)&sBh[(browRd + i * 16) * GT_PAD + koff];
      fbl[i] = *(const bfv8*)&sBl[(browRd + i * 16) * GT_PAD + koff];
    }
#pragma unroll
    for (int i = 0; i < 4; ++i)
#pragma unroll
      for (int j = 0; j < 4; ++j) {
        acc[i][j] = __builtin_amdgcn_mfma_f32_16x16x32_bf16(fah[i], fbh[j], acc[i][j], 0, 0, 0);
        acc[i][j] = __builtin_amdgcn_mfma_f32_16x16x32_bf16(fah[i], fbl[j], acc[i][j], 0, 0, 0);
        acc[i][j] = __builtin_amdgcn_mfma_f32_16x16x32_bf16(fal[i], fbh[j], acc[i][j], 0, 0, 0);
      }
  }

  const int crow0 = mBase + wr * 64 + ((lane >> 4) << 2);
  const int ccol0 = nBase + wc * 64 + (lane & 15);
#pragma unroll
  for (int j = 0; j < 4; ++j) {
    const int col = ccol0 + j * 16;
    const float bv = bias ? bias[col] : 0.f;
#pragma unroll
    for (int i = 0; i < 4; ++i) {
      const long rb = (long)(crow0 + i * 16) * N + col;
#pragma unroll
      for (int r = 0; r < 4; ++r)
        C[rb + (long)r * N] = acc[i][j][r] + bv;
    }
  }
}

// ---------------- per-(seg,h) outer products for ONE batch element ----------------
__global__ __launch_bounds__(256) void seg_outer(
    const float* __restrict__ Kf, const float* __restrict__ Vf,
    float* __restrict__ U, float* __restrict__ Zs) {
  const int sh = blockIdx.x;
  const int seg = sh >> 4, h = sh & 15;
  const int tid = threadIdx.x;
  const int dgrp = tid >> 6, e = tid & 63;
  __shared__ float sAK[16 * 64], sVv[16 * 64];
  const long base = ((long)seg * SEG_S) * D_DIM + h * 64;
  float acc[16] = {};
  float zacc = 0.f;
  for (int s0 = 0; s0 < SEG_S; s0 += 16) {
    __syncthreads();
#pragma unroll
    for (int r = 0; r < 4; ++r) {
      const int idx = r * 256 + tid;
      const int sl = idx >> 6, d = idx & 63;
      const long g = base + (long)(s0 + sl) * D_DIM + d;
      const float kv = Kf[g];
      sAK[idx] = kv > 0.f ? kv + 1.f : __expf(kv);
      sVv[idx] = Vf[g];
    }
    __syncthreads();
#pragma unroll
    for (int sl = 0; sl < 16; ++sl) {
      const float vv = sVv[sl * 64 + e];
#pragma unroll
      for (int i = 0; i < 16; ++i)
        acc[i] += sAK[sl * 64 + dgrp * 16 + i] * vv;
    }
    if (tid < 64) {
#pragma unroll
      for (int sl = 0; sl < 16; ++sl) zacc += sAK[sl * 64 + tid];
    }
  }
  const long ub = (long)sh * 4096;
#pragma unroll
  for (int i = 0; i < 16; ++i)
    U[ub + (dgrp * 16 + i) * 64 + e] = acc[i];
  if (tid < 64) Zs[(long)sh * 64 + tid] = zacc;
}

// ---------------- exclusive prefix over segments ----------------
__global__ __launch_bounds__(256) void seg_prefix(
    const float* __restrict__ U, const float* __restrict__ Zs,
    float* __restrict__ Mem, float* __restrict__ Zp) {
  const int h = blockIdx.x;
  const int tid = threadIdx.x;
  for (int j = tid; j < 4096; j += 256) {
    float run = 0.f;
#pragma unroll
    for (int t = 0; t < NSEG; ++t) {
      const long idx = ((long)(t * 16 + h)) * 4096 + j;
      Mem[idx] = run;
      run += U[idx];
    }
  }
  if (tid < 64) {
    float run = 0.f;
#pragma unroll
    for (int t = 0; t < NSEG; ++t) {
      const long idx = ((long)(t * 16 + h)) * 64 + tid;
      Zp[idx] = run;
      run += Zs[idx];
    }
  }
}

// ---------------- MFMA segment attention for ONE batch element ----------------
// block = 256 thr (4 waves x 16 queries), one (seg, h, 64-query tile) per block.
// S^T = mfma(K, Q): col=query=lane&15, row=key=4*(lane>>4)+reg (+16*kt).
__global__ __launch_bounds__(256) void attn_seg_mfma(
    const float* __restrict__ Qf, const float* __restrict__ Kf,
    const float* __restrict__ Vf, const int* __restrict__ mask,
    const float* __restrict__ Mem, const float* __restrict__ Zp,
    const float* __restrict__ betas,
    unsigned short* __restrict__ Oh, unsigned short* __restrict__ Ol) {
  __shared__ __bf16 sKh[64 * 72], sKl[64 * 72];     // K [key][d] (later Mem^T [e][d])
  __shared__ __bf16 sVTh[64 * 72], sVTl[64 * 72];   // V^T [e][key]
  __shared__ __bf16 sPh[4][16 * 72], sPl[4][16 * 72];  // per-wave P [q][key]
  __shared__ float sMaskF[64], sZ[64], sGate[64];

  const int bx = blockIdx.x;
  const int qblk = bx & 7, h = (bx >> 3) & 15, seg = bx >> 7;
  const int sh = seg * 16 + h;
  const int tid = threadIdx.x;
  const int lane = tid & 63, w = tid >> 6;
  const int g = lane >> 4, ln16 = lane & 15;

  // ---- Q fragments straight from global (one-time, 16 KiB/block) ----
  const int qglob = seg * SEG_S + qblk * 64 + w * 16 + ln16;
  const long qbase = (long)qglob * D_DIM + h * 64;
  bfv8 qh[2], ql[2];
#pragma unroll
  for (int dt = 0; dt < 2; ++dt) {
    fv4 a = *(const fv4*)&Qf[qbase + dt * 32 + g * 8];
    fv4 b2 = *(const fv4*)&Qf[qbase + dt * 32 + g * 8 + 4];
#pragma unroll
    for (int j = 0; j < 4; ++j) {
      unsigned short h0 = f2bf(a[j]);
      qh[dt][j] = __builtin_bit_cast(__bf16, h0);
      ql[dt][j] = __builtin_bit_cast(__bf16, f2bf(a[j] - bf2f(h0)));
      unsigned short h1 = f2bf(b2[j]);
      qh[dt][4 + j] = __builtin_bit_cast(__bf16, h1);
      ql[dt][4 + j] = __builtin_bit_cast(__bf16, f2bf(b2[j] - bf2f(h1)));
    }
  }

  fv4 O[4] = {};
  float m_run = -1e30f, l_run = 0.f;
  const long kvbase0 = (long)(seg * SEG_S) * D_DIM + h * 64;

  for (int c = 0; c < 8; ++c) {
    __syncthreads();
    // stage K chunk [64 keys][64 d] split-bf16
    {
      const int row = tid >> 2, ch = tid & 3;
#pragma unroll
      for (int r = 0; r < 2; ++r) {
        const int d0 = ch * 8 + r * 32;
        const long ga = kvbase0 + (long)(c * 64 + row) * D_DIM + d0;
        fv4 a = *(const fv4*)&Kf[ga];
        fv4 b2 = *(const fv4*)&Kf[ga + 4];
        u16v8 hv, lv;
#pragma unroll
        for (int j = 0; j < 4; ++j) {
          unsigned short h0 = f2bf(a[j]);
          hv[j] = h0; lv[j] = f2bf(a[j] - bf2f(h0));
          unsigned short h1 = f2bf(b2[j]);
          hv[4 + j] = h1; lv[4 + j] = f2bf(b2[j] - bf2f(h1));
        }
        *(u16v8*)&sKh[row * 72 + d0] = hv;
        *(u16v8*)&sKl[row * 72 + d0] = lv;
      }
    }
    // stage V^T chunk [64 e][64 keys] split-bf16 (quad-pack transpose)
    {
      const int e4 = (tid & 15) * 4, p4 = (tid >> 4) * 4;
      fv4 vv[4];
#pragma unroll
      for (int i = 0; i < 4; ++i)
        vv[i] = *(const fv4*)&Vf[kvbase0 + (long)(c * 64 + p4 + i) * D_DIM + e4];
#pragma unroll
      for (int je = 0; je < 4; ++je) {
        u16v4 hv, lv;
#pragma unroll
        for (int i = 0; i < 4; ++i) {
          unsigned short h0 = f2bf(vv[i][je]);
          hv[i] = h0; lv[i] = f2bf(vv[i][je] - bf2f(h0));
        }
        *(u16v4*)&sVTh[(e4 + je) * 72 + p4] = hv;
        *(u16v4*)&sVTl[(e4 + je) * 72 + p4] = lv;
      }
    }
    if (tid < 64) sMaskF[tid] = (mask[seg * SEG_S + c * 64 + tid] == 0) ? 1.f : 0.f;
    __syncthreads();

    // ---- S^T = K . Q^T (split 3-product) ----
    fv4 sc[4];
#pragma unroll
    for (int kt = 0; kt < 4; ++kt) {
      const int ro = (kt * 16 + ln16) * 72 + g * 8;
      bfv8 kh0 = *(const bfv8*)&sKh[ro], kh1 = *(const bfv8*)&sKh[ro + 32];
      bfv8 kl0 = *(const bfv8*)&sKl[ro], kl1 = *(const bfv8*)&sKl[ro + 32];
      fv4 s = {};
      s = __builtin_amdgcn_mfma_f32_16x16x32_bf16(kh0, qh[0], s, 0, 0, 0);
      s = __builtin_amdgcn_mfma_f32_16x16x32_bf16(kh1, qh[1], s, 0, 0, 0);
      s = __builtin_amdgcn_mfma_f32_16x16x32_bf16(kh0, ql[0], s, 0, 0, 0);
      s = __builtin_amdgcn_mfma_f32_16x16x32_bf16(kh1, ql[1], s, 0, 0, 0);
      s = __builtin_amdgcn_mfma_f32_16x16x32_bf16(kl0, qh[0], s, 0, 0, 0);
      s = __builtin_amdgcn_mfma_f32_16x16x32_bf16(kl1, qh[1], s, 0, 0, 0);
      sc[kt] = s;
    }
    // ---- online softmax (col=q in-lane; reduce across 4 lane-groups) ----
    float pmax = -3.0e38f;
#pragma unroll
    for (int kt = 0; kt < 4; ++kt)
#pragma unroll
      for (int r = 0; r < 4; ++r) {
        float v = sc[kt][r] * 0.125f;
        if (sMaskF[kt * 16 + g * 4 + r] != 0.f) v = -1e9f;
        sc[kt][r] = v;
        pmax = fmaxf(pmax, v);
      }
    pmax = fmaxf(pmax, __shfl_xor(pmax, 16));
    pmax = fmaxf(pmax, __shfl_xor(pmax, 32));
    const float m_new = fmaxf(m_run, pmax);
    const float resc = __expf(m_run - m_new);
    float psum = 0.f;
#pragma unroll
    for (int kt = 0; kt < 4; ++kt)
#pragma unroll
      for (int r = 0; r < 4; ++r) {
        const float p = __expf(sc[kt][r] - m_new);
        sc[kt][r] = p;
        psum += p;
      }
    psum += __shfl_xor(psum, 16);
    psum += __shfl_xor(psum, 32);
    l_run = l_run * resc + psum;
    m_run = m_new;
#pragma unroll
    for (int et = 0; et < 4; ++et)
#pragma unroll
      for (int r = 0; r < 4; ++r) O[et][r] *= resc;

    // ---- P -> per-wave LDS [q][key] split-bf16 ----
#pragma unroll
    for (int kt = 0; kt < 4; ++kt)
#pragma unroll
      for (int r2 = 0; r2 < 2; ++r2) {
        u16v2 hv, lv;
#pragma unroll
        for (int j = 0; j < 2; ++j) {
          const float p = sc[kt][r2 * 2 + j];
          unsigned short h0 = f2bf(p);
          hv[j] = h0; lv[j] = f2bf(p - bf2f(h0));
        }
        const int off = ln16 * 72 + kt * 16 + g * 4 + r2 * 2;
        *(u16v2*)&sPh[w][off] = hv;
        *(u16v2*)&sPl[w][off] = lv;
      }
    bfv8 pfh[2], pfl[2];
#pragma unroll
    for (int kt2 = 0; kt2 < 2; ++kt2) {
      pfh[kt2] = *(const bfv8*)&sPh[w][ln16 * 72 + kt2 * 32 + g * 8];
      pfl[kt2] = *(const bfv8*)&sPl[w][ln16 * 72 + kt2 * 32 + g * 8];
    }
    // ---- O^T += V^T . P (split 3-product) ----
#pragma unroll
    for (int et = 0; et < 4; ++et) {
      const int ro = (et * 16 + ln16) * 72 + g * 8;
      bfv8 vh0 = *(const bfv8*)&sVTh[ro], vh1 = *(const bfv8*)&sVTh[ro + 32];
      bfv8 vl0 = *(const bfv8*)&sVTl[ro], vl1 = *(const bfv8*)&sVTl[ro + 32];
      fv4 o = O[et];
      o = __builtin_amdgcn_mfma_f32_16x16x32_bf16(vh0, pfh[0], o, 0, 0, 0);
      o = __builtin_amdgcn_mfma_f32_16x16x32_bf16(vh1, pfh[1], o, 0, 0, 0);
      o = __builtin_amdgcn_mfma_f32_16x16x32_bf16(vh0, pfl[0], o, 0, 0, 0);
      o = __builtin_amdgcn_mfma_f32_16x16x32_bf16(vh1, pfl[1], o, 0, 0, 0);
      o = __builtin_amdgcn_mfma_f32_16x16x32_bf16(vl0, pfh[0], o, 0, 0, 0);
      o = __builtin_amdgcn_mfma_f32_16x16x32_bf16(vl1, pfh[1], o, 0, 0, 0);
      O[et] = o;
    }
  }

  // ---- memory-read term ----
  __syncthreads();
  {  // stage Mem^T [e][d] into sKh/sKl (quad-pack transpose)
    const int e4 = (tid & 15) * 4, p4 = (tid >> 4) * 4;
    const float* Memp = Mem + (long)sh * 4096;
    fv4 mv[4];
#pragma unroll
    for (int i = 0; i < 4; ++i) mv[i] = *(const fv4*)&Memp[(p4 + i) * 64 + e4];
#pragma unroll
    for (int je = 0; je < 4; ++je) {
      u16v4 hv, lv;
#pragma unroll
      for (int i = 0; i < 4; ++i) {
        unsigned short h0 = f2bf(mv[i][je]);
        hv[i] = h0; lv[i] = f2bf(mv[i][je] - bf2f(h0));
      }
      *(u16v4*)&sKh[(e4 + je) * 72 + p4] = hv;
      *(u16v4*)&sKl[(e4 + je) * 72 + p4] = lv;
    }
  }
  if (tid < 64) {
    sZ[tid] = Zp[(long)sh * 64 + tid];
    sGate[tid] = 1.f / (1.f + __expf(-betas[h * 64 + tid]));
  }
  __syncthreads();

  // aq = elu(q)+1 in-register (reuse q frags); denom = aq . z
  float dpart = 0.f;
#pragma unroll
  for (int dt = 0; dt < 2; ++dt) {
    bfv8 ah, al;
#pragma unroll
    for (int j = 0; j < 8; ++j) {
      const float x = (float)qh[dt][j] + (float)ql[dt][j];
      const float a = x > 0.f ? x + 1.f : __expf(x);
      dpart += a * sZ[dt * 32 + g * 8 + j];
      unsigned short h0 = f2bf(a);
      ah[j] = __builtin_bit_cast(__bf16, h0);
      al[j] = __builtin_bit_cast(__bf16, f2bf(a - bf2f(h0)));
    }
    qh[dt] = ah;
    ql[dt] = al;
  }
  dpart += __shfl_xor(dpart, 16);
  dpart += __shfl_xor(dpart, 32);
  const float invden = 1.f / (dpart + 1e-9f);
  const float invl = 1.f / l_run;

  fv4 amem[4] = {};
#pragma unroll
  for (int et = 0; et < 4; ++et) {
    const int ro = (et * 16 + ln16) * 72 + g * 8;
    bfv8 mh0 = *(const bfv8*)&sKh[ro], mh1 = *(const bfv8*)&sKh[ro + 32];
    bfv8 ml0 = *(const bfv8*)&sKl[ro], ml1 = *(const bfv8*)&sKl[ro + 32];
    fv4 o = amem[et];
    o = __builtin_amdgcn_mfma_f32_16x16x32_bf16(mh0, qh[0], o, 0, 0, 0);
    o = __builtin_amdgcn_mfma_f32_16x16x32_bf16(mh1, qh[1], o, 0, 0, 0);
    o = __builtin_amdgcn_mfma_f32_16x16x32_bf16(mh0, ql[0], o, 0, 0, 0);
    o = __builtin_amdgcn_mfma_f32_16x16x32_bf16(mh1, ql[1], o, 0, 0, 0);
    o = __builtin_amdgcn_mfma_f32_16x16x32_bf16(ml0, qh[0], o, 0, 0, 0);
    o = __builtin_amdgcn_mfma_f32_16x16x32_bf16(ml1, qh[1], o, 0, 0, 0);
    amem[et] = o;
  }

  // ---- gate combine + split-bf16 store ----
  const long obase = (long)qglob * D_DIM + h * 64;
#pragma unroll
  for (int et = 0; et < 4; ++et) {
    u16v4 hv, lv;
#pragma unroll
    for (int r = 0; r < 4; ++r) {
      const int e = et * 16 + g * 4 + r;
      const float gt = sGate[e];
      const float att = gt * amem[et][r] * invden + (1.f - gt) * O[et][r] * invl;
      unsigned short h0 = f2bf(att);
      hv[r] = h0;
      lv[r] = f2bf(att - bf2f(h0));
    }
    *(u16v4*)&Oh[obase + et * 16 + g * 4] = hv;
    *(u16v4*)&Ol[obase + et * 16 + g * 4] = lv;
  }
}

// ---------------- host launch: batch-tiled to bound workspace ----------------
extern "C" void kernel_launch(void* const* d_in, const int* in_sizes, int n_in,
                              void* d_out, int out_size, void* d_ws, size_t ws_size,
                              hipStream_t stream) {
  (void)in_sizes; (void)n_in; (void)out_size;
  const float* x     = (const float*)d_in[0];
  const int*   mask  = (const int*)d_in[1];
  const float* wq    = (const float*)d_in[2];
  const float* wk    = (const float*)d_in[3];
  const float* wv    = (const float*)d_in[4];
  const float* wo    = (const float*)d_in[5];
  const float* wob   = (const float*)d_in[6];
  const float* betas = (const float*)d_in[7];
  float* out = (float*)d_out;

  const size_t TOKB = (size_t)MB_TOK * D_DIM;
  char* ws = (char*)d_ws;
  size_t off = 0;
  auto alloc = [&](size_t bytes) {
    char* p = ws + off;
    off += (bytes + 255) & ~(size_t)255;
    return p;
  };
  unsigned short* wsp[8];
  for (int i = 0; i < 8; ++i)
    wsp[i] = (unsigned short*)alloc((size_t)D_DIM * D_DIM * 2);
  unsigned short* xh = (unsigned short*)alloc(TOKB * 2);
  unsigned short* xl = (unsigned short*)alloc(TOKB * 2);
  float* qf = (float*)alloc(TOKB * 4);
  float* kf = (float*)alloc(TOKB * 4);
  float* vf = (float*)alloc(TOKB * 4);
  float* U   = (float*)alloc((size_t)NSEG * H_NUM * 4096 * 4);
  float* Mem = (float*)alloc((size_t)NSEG * H_NUM * 4096 * 4);
  float* Zs  = (float*)alloc((size_t)NSEG * H_NUM * 64 * 4);
  float* Zp  = (float*)alloc((size_t)NSEG * H_NUM * 64 * 4);
  unsigned short* atth = xh;
  unsigned short* attl = xl;

  if (off > ws_size) return;

  const float* wsrc[4] = {wq, wk, wv, wo};
  for (int i = 0; i < 4; ++i)
    split_f32_bf16x2<<<1024, 256, 0, stream>>>(wsrc[i], wsp[2 * i], wsp[2 * i + 1],
                                               D_DIM * D_DIM / 4);

  dim3 ggrid(D_DIM / 128, MB_TOK / 128);
  for (int b = 0; b < B_DIM; ++b) {
    const float* xb = x + (size_t)b * TOKB;
    const int* maskb = mask + (size_t)b * L_DIM;
    float* outb = out + (size_t)b * TOKB;

    split_f32_bf16x2<<<2048, 256, 0, stream>>>(xb, xh, xl, (int)(TOKB / 4));

    gemm_bt_split<<<ggrid, 256, 0, stream>>>(
        (const __bf16*)xh, (const __bf16*)xl, (const __bf16*)wsp[0], (const __bf16*)wsp[1],
        qf, nullptr, MB_TOK, D_DIM, D_DIM);
    gemm_bt_split<<<ggrid, 256, 0, stream>>>(
        (const __bf16*)xh, (const __bf16*)xl, (const __bf16*)wsp[2], (const __bf16*)wsp[3],
        kf, nullptr, MB_TOK, D_DIM, D_DIM);
    gemm_bt_split<<<ggrid, 256, 0, stream>>>(
        (const __bf16*)xh, (const __bf16*)xl, (const __bf16*)wsp[4], (const __bf16*)wsp[5],
        vf, nullptr, MB_TOK, D_DIM, D_DIM);

    seg_outer<<<NSEG * H_NUM, 256, 0, stream>>>(kf, vf, U, Zs);
    seg_prefix<<<H_NUM, 256, 0, stream>>>(U, Zs, Mem, Zp);

    attn_seg_mfma<<<NSEG * H_NUM * 8, 256, 0, stream>>>(qf, kf, vf, maskb, Mem, Zp, betas,
                                                        atth, attl);

    gemm_bt_split<<<ggrid, 256, 0, stream>>>(
        (const __bf16*)atth, (const __bf16*)attl, (const __bf16*)wsp[6], (const __bf16*)wsp[7],
        outb, wob, MB_TOK, D_DIM, D_DIM);
  }
}